// Round 6
// baseline (209.599 us; speedup 1.0000x reference)
//
#include <hip/hip_runtime.h>
#include <hip/hip_bf16.h>

typedef __bf16  bf16x8  __attribute__((ext_vector_type(8)));
typedef float   floatx4 __attribute__((ext_vector_type(4)));

#define ROWLEN      4096                  // floats per sample row (2048 sites x 2 phys)
#define B_SAMPLES   8192

typedef const __attribute__((address_space(1))) void* gas1_t;
typedef __attribute__((address_space(3))) void*       las3_t;

__device__ __forceinline__ void stage16(const float* g, float* l) {
    // global -> LDS direct, 16 B per lane; LDS dest = uniform base + lane*16
    __builtin_amdgcn_global_load_lds((gas1_t)g, (las3_t)l, 16, 0, 0);
}

// ws layout: [0, 524288) bf16 weight fragments (MFMA B-operand order).
// Fragment layout (bf16x8 per lane, MFMA 16x16x32 B-operand order):
//   frag g = ((h*64 + t)*4 + nt)*64 + lane ; element j (0..7)
//   holds W_h[kk = t*32 + (lane>>4)*8 + j][n = nt*16 + (lane&15)]
// K padded to 2048 per half: h=0 zero-weights kk<2, h=1 zero-weights site 2047.

// 128 blocks x 256 threads: one thread per fragment (8 bf16 = 16 B store).
__global__ __launch_bounds__(256) void repack_kernel(
    const float* __restrict__ left, const float* __restrict__ right,
    __bf16* __restrict__ wfrag)
{
    __shared__ float norms[2];
    const int tid  = threadIdx.x;
    const int wv   = tid >> 6;
    const int ln   = tid & 63;

    if (wv < 2) {
        const float* W = (wv == 0) ? left : right;
        float a = W[384 + ln], b = W[384 + 64 + ln];
        float s = a * a + b * b;
        s += __shfl_xor(s, 1);  s += __shfl_xor(s, 2);  s += __shfl_xor(s, 4);
        s += __shfl_xor(s, 8);  s += __shfl_xor(s, 16); s += __shfl_xor(s, 32);
        if (ln == 0) norms[wv] = 1.0f / sqrtf(s);
    }
    __syncthreads();
    const float invL = norms[0];
    const float invR = norms[1];

    const int g    = (int)(blockIdx.x * 256) + tid;   // fragment index [0,32768)
    const int lane = g & 63;
    const int nt   = (g >> 6) & 3;
    const int t    = (g >> 8) & 63;
    const int h    = (g >> 14) & 1;
    const int kk0  = t * 32 + (lane >> 4) * 8;
    const int n    = nt * 16 + (lane & 15);
    const int a    = n >> 3, bb = n & 7;
    const float* W = (h == 0) ? left : right;

    bf16x8 frag;
#pragma unroll
    for (int si = 0; si < 4; ++si) {
        const int kk = kk0 + si * 2;
        int s;  bool valid;
        if (h == 0) { s = (kk >> 1) - 1; valid = (kk >= 2); }
        else        { s = (kk >> 1);     valid = (s < 1023); }
        float w0 = 0.f, w1 = 0.f;
        if (valid) {
            const float* wp = W + ((s * 8 + a) * 8 + bb) * 2;
            w0 = wp[0]; w1 = wp[1];
            if (s == 3) { const float sc = (h == 0) ? invL : invR; w0 *= sc; w1 *= sc; }
        }
        frag[si * 2]     = (__bf16)w0;
        frag[si * 2 + 1] = (__bf16)w1;
    }
    ((bf16x8*)wfrag)[g] = frag;
}

// 512 blocks x 512 threads, 1 block/CU (128 KB LDS). DEEP-ROW streaming:
// 16 samples/block; 4 phases, each staging 16 rows x 4 KB where phase p covers
// cols [p*1024, p*1024+1024) -- every row is consumed as ONE contiguous
// 16 KB stream across the kernel (DRAM page-friendly), instead of 8192
// fine-grained strided streams. Each wave stages 2 rows as 4 back-to-back
// 1 KB global_load_lds per phase (granule-XOR pre-swizzled source, linear
// LDS dest; reads un-swizzle -- rule #21 both-sides scheme, same as R5).
// Compute split: wave = (nt-group ntp = wid&3, K-half kkp = wid>>2); every
// wave computes every phase; NO cross-wave K reduction until a final 2-term
// LDS combine. Pipeline per phase (R5's proven discipline):
//   [stage(next)] [vmcnt(8): next stays in flight, current guaranteed landed]
//   [s_barrier] [compute] [s_barrier].
__global__ __launch_bounds__(512, 2) void mps_main_kernel(
    const float* __restrict__ x, const __bf16* __restrict__ wfrag,
    const float* __restrict__ left_b, const float* __restrict__ right_b,
    float* __restrict__ out)
{
    __shared__ float buf[2][16][1024];   // 2 x 64 KB ping-pong
    const int tid  = threadIdx.x;
    const int wid  = tid >> 6;           // 8 waves
    const int lane = tid & 63;
    const int ntp  = wid & 3;            // output column group (16 cols)
    const int kkp  = wid >> 2;           // K-half within each 1024-col phase
    const int mcol = lane & 15;          // sample row (A) / D col
    const int q    = lane >> 4;
    const int sx   = mcol & 7;           // read-side granule XOR
    const int blk  = blockIdx.x;

    const float* xblk = x + (size_t)blk * 16 * ROWLEN;
    const bf16x8* wf  = (const bf16x8*)wfrag;

    // ---- staging: wave stages rows 2*wid, 2*wid+1; 4 x 1 KB each, sequential
    auto STAGE = [&](int w, int b) {
#pragma unroll
        for (int rr = 0; rr < 2; ++rr) {
            const int r = 2 * wid + rr;
            const int sxor = r & 7;
            const float* grow = xblk + (size_t)r * ROWLEN + w * 1024;
#pragma unroll
            for (int gi = 0; gi < 4; ++gi) {
                const float* gp = grow + (gi * 64 + (lane ^ sxor)) * 4;
                stage16(gp, &buf[b][r][gi * 256]);
            }
        }
    };

    floatx4 accL = {0.f,0.f,0.f,0.f};    // h=0 result (16 samples x 16 cols)
    floatx4 accR = {0.f,0.f,0.f,0.f};    // h=1 result

    // ---- compute: 16 tl of {2 swizzled ds_read_b128, cvt, 1 MFMA}
    auto COMPUTE = [&](int w, int b, floatx4& acc) {
        const int h = w >> 1;
#pragma unroll
        for (int g4 = 0; g4 < 4; ++g4) {
            bf16x8 wv[4];
#pragma unroll
            for (int j = 0; j < 4; ++j) {
                const int t = (w & 1) * 32 + kkp * 16 + g4 * 4 + j;
                wv[j] = wf[((size_t)((h * 64 + t) * 4 + ntp)) * 64 + lane];
            }
#pragma unroll
            for (int j = 0; j < 4; ++j) {
                const int tl = g4 * 4 + j;
                const int gg = kkp * 128 + tl * 8 + 2 * q;
                const floatx4 a0 = *(const floatx4*)&buf[b][mcol][((gg    ) ^ sx) * 4];
                const floatx4 a1 = *(const floatx4*)&buf[b][mcol][((gg + 1) ^ sx) * 4];
                bf16x8 af;
                af[0] = (__bf16)a0[0]; af[1] = (__bf16)a0[1];
                af[2] = (__bf16)a0[2]; af[3] = (__bf16)a0[3];
                af[4] = (__bf16)a1[0]; af[5] = (__bf16)a1[1];
                af[6] = (__bf16)a1[2]; af[7] = (__bf16)a1[3];
                acc = __builtin_amdgcn_mfma_f32_16x16x32_bf16(af, wv[j], acc, 0, 0, 0);
            }
        }
    };

    STAGE(0, 0);                          // prologue: phase-0 window

#pragma unroll
    for (int p = 0; p < 4; ++p) {
        if (p < 3) STAGE(p + 1, (p + 1) & 1);
        __builtin_amdgcn_sched_barrier(0);
        if (p < 3) asm volatile("s_waitcnt vmcnt(8)" ::: "memory");
        else       asm volatile("s_waitcnt vmcnt(0)" ::: "memory");
        __builtin_amdgcn_s_barrier();
        __builtin_amdgcn_sched_barrier(0);
        if (p < 2) COMPUTE(p, p & 1, accL);
        else       COMPUTE(p, p & 1, accR);
        __builtin_amdgcn_sched_barrier(0);
        __builtin_amdgcn_s_barrier();
    }

    // ---- reduce area overlays buf[0] (dead after phase-2 compute + barrier)
    float* red = &buf[0][0][0];           // red[h][kk][s][68]
#pragma unroll
    for (int i = 0; i < 4; ++i) {
        const int s = q * 4 + i;
        red[((0 * 2 + kkp) * 16 + s) * 68 + ntp * 16 + mcol] = accL[i];
        red[((1 * 2 + kkp) * 16 + s) * 68 + ntp * 16 + mcol] = accR[i];
    }
    __syncthreads();

    if (tid < 128) {
        const int s  = tid >> 3;          // sample within block (0..15)
        const int b2 = tid & 7;           // bond index b
        const size_t k = (size_t)blk * 16 + s;
        const float* xr = x + k * ROWLEN;
        const float x0 = xr[0],    x1 = xr[1];        // x[k, 0, :]
        const float y0 = xr[4094], y1 = xr[4095];     // x[k, 2047, :]
        const float lbn = 1.0f / sqrtf(left_b[4]*left_b[4] + left_b[5]*left_b[5]);
        const float rbn = 1.0f / sqrtf(right_b[4]*right_b[4] + right_b[5]*right_b[5]);
        float l = 0.f, r = 0.f;
#pragma unroll
        for (int a = 0; a < 8; ++a) {
            float lv = left_b[a*2]  * x0 + left_b[a*2+1]  * x1;
            float rv = right_b[a*2] * y0 + right_b[a*2+1] * y1;
            if (a == 2) { lv *= lbn; rv *= rbn; }
            const int n = a * 8 + b2;
            const float ls = red[((0*2+0)*16 + s)*68 + n] + red[((0*2+1)*16 + s)*68 + n];
            const float rs = red[((1*2+0)*16 + s)*68 + n] + red[((1*2+1)*16 + s)*68 + n];
            l += lv * ls;
            r += rv * rs;
        }
        float vv = l * r;
        vv += __shfl_xor(vv, 1);
        vv += __shfl_xor(vv, 2);
        vv += __shfl_xor(vv, 4);
        if (b2 == 0) out[k] = vv;
    }
}

extern "C" void kernel_launch(void* const* d_in, const int* in_sizes, int n_in,
                              void* d_out, int out_size, void* d_ws, size_t ws_size,
                              hipStream_t stream)
{
    const float* x       = (const float*)d_in[0];
    const float* left_b  = (const float*)d_in[1];
    const float* left    = (const float*)d_in[2];
    const float* right   = (const float*)d_in[3];
    const float* right_b = (const float*)d_in[4];

    __bf16* wfrag = (__bf16*)d_ws;
    float*  out   = (float*)d_out;

    hipLaunchKernelGGL(repack_kernel, dim3(128), dim3(256), 0, stream,
                       left, right, wfrag);
    hipLaunchKernelGGL(mps_main_kernel, dim3(B_SAMPLES / 16), dim3(512), 0, stream,
                       x, wfrag, left_b, right_b, out);
}

// Round 7
// 201.110 us; speedup vs baseline: 1.0422x; 1.0422x over previous
//
#include <hip/hip_runtime.h>
#include <hip/hip_bf16.h>

typedef __bf16  bf16x8  __attribute__((ext_vector_type(8)));
typedef float   floatx4 __attribute__((ext_vector_type(4)));

#define ROWLEN      4096                  // floats per sample row (2048 sites x 2 phys)
#define B_SAMPLES   8192
#define FRAG_ELEMS  (2*64*4*64*8)         // 262144 bf16 = 512 KB

// ws layout: [0, 524288) bf16 weight fragments (MFMA B-operand order).
//
// Fragment layout (bf16x8 per lane, MFMA 16x16x32 B-operand order):
//   frag g = ((h*64 + t)*4 + nt)*64 + lane ; element j (0..7)
//   holds W_h[kk = t*32 + (lane>>4)*8 + j][n = nt*16 + (lane&15)]
// K padded to 2048 per half: h=0 zero-weights kk<2 (site 0 = boundary),
// h=1 zero-weights site 2047 (boundary). Every A-load in main is a
// 16B-aligned float4 inside the sample's own contiguous row.

// 128 blocks x 256 threads: one thread per fragment (8 bf16 = 16 B store).
__global__ __launch_bounds__(256) void repack_kernel(
    const float* __restrict__ left, const float* __restrict__ right,
    __bf16* __restrict__ wfrag)
{
    __shared__ float norms[2];
    const int tid  = threadIdx.x;
    const int wv   = tid >> 6;
    const int ln   = tid & 63;

    // Frobenius norms of left[3]/right[3] (128 floats each at offset 384):
    // wave 0 -> left, wave 1 -> right, shuffle reduction, single sync.
    if (wv < 2) {
        const float* W = (wv == 0) ? left : right;
        float a = W[384 + ln], b = W[384 + 64 + ln];
        float s = a * a + b * b;
        s += __shfl_xor(s, 1);  s += __shfl_xor(s, 2);  s += __shfl_xor(s, 4);
        s += __shfl_xor(s, 8);  s += __shfl_xor(s, 16); s += __shfl_xor(s, 32);
        if (ln == 0) norms[wv] = 1.0f / sqrtf(s);
    }
    __syncthreads();
    const float invL = norms[0];
    const float invR = norms[1];

    const int g    = (int)(blockIdx.x * 256) + tid;   // fragment index [0,32768)
    const int lane = g & 63;
    const int nt   = (g >> 6) & 3;
    const int t    = (g >> 8) & 63;
    const int h    = (g >> 14) & 1;
    const int kk0  = t * 32 + (lane >> 4) * 8;        // first kk of this frag
    const int n    = nt * 16 + (lane & 15);
    const int a    = n >> 3, bb = n & 7;
    const float* W = (h == 0) ? left : right;

    bf16x8 frag;
#pragma unroll
    for (int si = 0; si < 4; ++si) {
        const int kk = kk0 + si * 2;                  // p=0 element; p=1 is kk+1
        int s;  bool valid;
        if (h == 0) { s = (kk >> 1) - 1; valid = (kk >= 2); }
        else        { s = (kk >> 1);     valid = (s < 1023); }
        float w0 = 0.f, w1 = 0.f;
        if (valid) {
            const float* wp = W + ((s * 8 + a) * 8 + bb) * 2;
            w0 = wp[0]; w1 = wp[1];
            if (s == 3) { const float sc = (h == 0) ? invL : invR; w0 *= sc; w1 *= sc; }
        }
        frag[si * 2]     = (__bf16)w0;
        frag[si * 2 + 1] = (__bf16)w1;
    }
    ((bf16x8*)wfrag)[g] = frag;
}

// 256 blocks x 512 threads. Wave w (0..7): h = w&1, K-chunk c = w>>1 (K=512).
// 32 samples per block: each wave computes TWO M=16 tiles sharing the same
// B-fragments (halves wfrag L2 traffic per sample, 8 MFMAs : 4 B-loads).
// R7 probe: plain cached loads for x (nontemporal hint removed) -- single
// variable A/B against the proven-best R0 structure.
__global__ __launch_bounds__(512, 2) void mps_main_kernel(
    const float* __restrict__ x, const __bf16* __restrict__ wfrag,
    const float* __restrict__ left_b, const float* __restrict__ right_b,
    float* __restrict__ out)
{
    __shared__ float lds[2][4][32][65];   // [half][kchunk][sample][n], padded
    const int tid  = threadIdx.x;
    const int wid  = tid >> 6;            // 8 waves
    const int lane = tid & 63;
    const int h    = wid & 1;
    const int c    = wid >> 1;            // 0..3
    const int mcol = lane & 15;           // A row (sample) on load; D col on store
    const int q    = lane >> 4;
    const int blk  = blockIdx.x;

    const float* arow0 = x + (size_t)(blk * 32 + mcol) * ROWLEN
                           + h * 2048 + c * 512 + q * 8;
    const float* arow1 = arow0 + (size_t)16 * ROWLEN;
    const bf16x8* bbase = (const bf16x8*)wfrag
                          + ((size_t)(h * 64 + c * 16) * 4) * 64 + lane;

    floatx4 accA0 = {0.f,0.f,0.f,0.f}, accA1 = {0.f,0.f,0.f,0.f};
    floatx4 accA2 = {0.f,0.f,0.f,0.f}, accA3 = {0.f,0.f,0.f,0.f};
    floatx4 accB0 = {0.f,0.f,0.f,0.f}, accB1 = {0.f,0.f,0.f,0.f};
    floatx4 accB2 = {0.f,0.f,0.f,0.f}, accB3 = {0.f,0.f,0.f,0.f};

#pragma unroll 4
    for (int tl = 0; tl < 16; ++tl) {
        const floatx4* ap0 = (const floatx4*)(arow0 + tl * 32);
        const floatx4* ap1 = (const floatx4*)(arow1 + tl * 32);
        const floatx4 a0 = ap0[0];
        const floatx4 a1 = ap0[1];
        const floatx4 b0 = ap1[0];
        const floatx4 b1 = ap1[1];
        bf16x8 af0, af1;
        af0[0] = (__bf16)a0[0]; af0[1] = (__bf16)a0[1];
        af0[2] = (__bf16)a0[2]; af0[3] = (__bf16)a0[3];
        af0[4] = (__bf16)a1[0]; af0[5] = (__bf16)a1[1];
        af0[6] = (__bf16)a1[2]; af0[7] = (__bf16)a1[3];
        af1[0] = (__bf16)b0[0]; af1[1] = (__bf16)b0[1];
        af1[2] = (__bf16)b0[2]; af1[3] = (__bf16)b0[3];
        af1[4] = (__bf16)b1[0]; af1[5] = (__bf16)b1[1];
        af1[6] = (__bf16)b1[2]; af1[7] = (__bf16)b1[3];
        const bf16x8* bp = bbase + (size_t)tl * 256;
        const bf16x8 w0 = bp[0], w1 = bp[64], w2 = bp[128], w3 = bp[192];
        accA0 = __builtin_amdgcn_mfma_f32_16x16x32_bf16(af0, w0, accA0, 0, 0, 0);
        accB0 = __builtin_amdgcn_mfma_f32_16x16x32_bf16(af1, w0, accB0, 0, 0, 0);
        accA1 = __builtin_amdgcn_mfma_f32_16x16x32_bf16(af0, w1, accA1, 0, 0, 0);
        accB1 = __builtin_amdgcn_mfma_f32_16x16x32_bf16(af1, w1, accB1, 0, 0, 0);
        accA2 = __builtin_amdgcn_mfma_f32_16x16x32_bf16(af0, w2, accA2, 0, 0, 0);
        accB2 = __builtin_amdgcn_mfma_f32_16x16x32_bf16(af1, w2, accB2, 0, 0, 0);
        accA3 = __builtin_amdgcn_mfma_f32_16x16x32_bf16(af0, w3, accA3, 0, 0, 0);
        accB3 = __builtin_amdgcn_mfma_f32_16x16x32_bf16(af1, w3, accB3, 0, 0, 0);
    }

    // C/D layout: lane holds D[row = q*4+i][col = lane&15]; row = sample-in-tile
#pragma unroll
    for (int i = 0; i < 4; ++i) {
        const int r0 = q * 4 + i;
        lds[h][c][r0][ 0 + mcol] = accA0[i];
        lds[h][c][r0][16 + mcol] = accA1[i];
        lds[h][c][r0][32 + mcol] = accA2[i];
        lds[h][c][r0][48 + mcol] = accA3[i];
        lds[h][c][16 + r0][ 0 + mcol] = accB0[i];
        lds[h][c][16 + r0][16 + mcol] = accB1[i];
        lds[h][c][16 + r0][32 + mcol] = accB2[i];
        lds[h][c][16 + r0][48 + mcol] = accB3[i];
    }
    __syncthreads();

    if (tid < 256) {
        const int mm = tid >> 3;          // sample within block (0..31)
        const int b  = tid & 7;           // bond index b
        const size_t k = (size_t)blk * 32 + mm;
        const float* xr = x + k * ROWLEN;
        const float x0 = xr[0],    x1 = xr[1];        // x[k, 0, :]
        const float y0 = xr[4094], y1 = xr[4095];     // x[k, 2047, :]
        // boundary vectors inline (row 2 normalized), wave-uniform loads
        const float lbn = 1.0f / sqrtf(left_b[4]*left_b[4] + left_b[5]*left_b[5]);
        const float rbn = 1.0f / sqrtf(right_b[4]*right_b[4] + right_b[5]*right_b[5]);
        float l = 0.f, r = 0.f;
#pragma unroll
        for (int a = 0; a < 8; ++a) {
            float lv = left_b[a*2]  * x0 + left_b[a*2+1]  * x1;
            float rv = right_b[a*2] * y0 + right_b[a*2+1] * y1;
            if (a == 2) { lv *= lbn; rv *= rbn; }
            const int n = a * 8 + b;
            const float ls = lds[0][0][mm][n] + lds[0][1][mm][n]
                           + lds[0][2][mm][n] + lds[0][3][mm][n];
            const float rs = lds[1][0][mm][n] + lds[1][1][mm][n]
                           + lds[1][2][mm][n] + lds[1][3][mm][n];
            l += lv * ls;
            r += rv * rs;
        }
        float vv = l * r;
        vv += __shfl_xor(vv, 1);
        vv += __shfl_xor(vv, 2);
        vv += __shfl_xor(vv, 4);
        if (b == 0) out[k] = vv;
    }
}

extern "C" void kernel_launch(void* const* d_in, const int* in_sizes, int n_in,
                              void* d_out, int out_size, void* d_ws, size_t ws_size,
                              hipStream_t stream)
{
    const float* x       = (const float*)d_in[0];
    const float* left_b  = (const float*)d_in[1];
    const float* left    = (const float*)d_in[2];
    const float* right   = (const float*)d_in[3];
    const float* right_b = (const float*)d_in[4];

    __bf16* wfrag = (__bf16*)d_ws;
    float*  out   = (float*)d_out;

    hipLaunchKernelGGL(repack_kernel, dim3(128), dim3(256), 0, stream,
                       left, right, wfrag);
    hipLaunchKernelGGL(mps_main_kernel, dim3(B_SAMPLES / 32), dim3(512), 0, stream,
                       x, wfrag, left_b, right_b, out);
}